// Round 4
// baseline (379.066 us; speedup 1.0000x reference)
//
#include <hip/hip_runtime.h>

// HMM trajectory forward, rank-1+diag rewrite, scaled-probability space.
// R4: producer/consumer wave specialization. One block (4 waves) per batch
// element. Waves 1-3 load globals + exp -> LDS ring; wave 0 runs the serial
// chain from LDS only. lane = state (b==64).

#define CHUNK 32
#define PF 4
#define NPS 11   // ceil(CHUNK/3) producer slots per wave

template <int CTRL, int RMASK>
__device__ __forceinline__ float dpp_add(float x) {
    int yi = __builtin_amdgcn_update_dpp(
        0, __builtin_bit_cast(int, x), CTRL, RMASK, 0xf, true);
    return x + __builtin_bit_cast(float, yi);
}

// sum over 64 lanes -> wave-uniform scalar
__device__ __forceinline__ float wave_sum64(float x) {
    x = dpp_add<0x111, 0xf>(x);   // row_shr:1
    x = dpp_add<0x112, 0xf>(x);   // row_shr:2
    x = dpp_add<0x114, 0xf>(x);   // row_shr:4
    x = dpp_add<0x118, 0xf>(x);   // row_shr:8
    x = dpp_add<0x142, 0xa>(x);   // row_bcast:15 -> rows 1,3
    x = dpp_add<0x143, 0xc>(x);   // row_bcast:31 -> row 3
    return __builtin_bit_cast(float,
        __builtin_amdgcn_readlane(__builtin_bit_cast(int, x), 63));
}

__global__ __launch_bounds__(256)
void hmm_fwd(const float* __restrict__ stop,     // (B, T+1, 64, 2)
             const float* __restrict__ start,    // (B, T+1, 64)
             const float* __restrict__ act,      // (B, T+1, 64, A)
             const int*   __restrict__ actions,  // (B, T)
             const int*   __restrict__ lengths,  // (B,)
             float* __restrict__ out,            // scalar
             int T, int A)
{
    const int bi   = blockIdx.x;
    const int tid  = threadIdx.x;
    const int wave = tid >> 6;
    const int lane = tid & 63;
    const int Tp1  = T + 1;
    const int NB   = 64;
    const int rowA = NB * A;

    const float* stopP  = stop  + (size_t)bi * Tp1 * NB * 2 + lane * 2;
    const float* startP = start + (size_t)bi * Tp1 * NB     + lane;
    const float* actP   = act   + (size_t)bi * Tp1 * NB * A + lane * A;
    const int*   actsB  = actions + (size_t)bi * T;

    const int L   = lengths[bi];          // uniform across block
    const int Lm1 = L - 1;
    const int nch = (Lm1 + CHUNK - 1) / CHUNK;

    __shared__ int   actsL[1024];
    __shared__ float pe1[2][CHUNK][64];   // exp(ch + st)
    __shared__ float pe2[2][CHUNK][64];   // exp(ch + om)
    __shared__ float peb[2][CHUNK][64];   // exp(beta)

    for (int i = tid; i < T; i += 256) actsL[i] = actsB[i];
    __syncthreads();

    // ---- consumer state (wave 0) ----
    float p  = (lane == 0) ? 1.0f : 0.0f;
    float C2 = 0.0f;
    float blv = 0.0f;
    if (wave == 0) blv = stopP[(size_t)L * (NB * 2)];   // beta[L] (STOP comp)

    // ---- producer state (waves 1-3) ----
    const int w = wave - 1;
    float fB[2][NPS], fO[2][NPS], fS[2][NPS], fC[2][NPS];

    auto p_load = [&](int buf, int c) {
        #pragma unroll
        for (int s = 0; s < NPS; ++s) {
            const int jj = w + 3 * s;
            if (jj < CHUNK) {
                const int t = min(1 + c * CHUNK + jj, Lm1);
                const float2 so = *(const float2*)(stopP + (size_t)t * (NB * 2));
                fB[buf][s] = so.x;
                fO[buf][s] = so.y;
                fS[buf][s] = startP[(size_t)t * NB];
                fC[buf][s] = actP[(size_t)t * rowA + actsL[t]];
            }
        }
    };
    auto p_write = [&](int buf, int c) {
        const int slot = c & 1;
        #pragma unroll
        for (int s = 0; s < NPS; ++s) {
            const int jj = w + 3 * s;
            if (jj < CHUNK) {
                pe1[slot][jj][lane] = __expf(fC[buf][s] + fS[buf][s]);
                pe2[slot][jj][lane] = __expf(fC[buf][s] + fO[buf][s]);
                peb[slot][jj][lane] = __expf(fB[buf][s]);
            }
        }
    };
    auto consume = [&](int cc) {
        const int slot = cc & 1;
        const int cnt  = min(CHUNK, Lm1 - cc * CHUNK);
        const float* b1 = &pe1[slot][0][lane];
        const float* b2 = &pe2[slot][0][lane];
        const float* b3 = &peb[slot][0][lane];
        float r1[PF], r2[PF], rb[PF];
        #pragma unroll
        for (int i = 0; i < PF; ++i) {
            r1[i] = b1[i * 64]; r2[i] = b2[i * 64]; rb[i] = b3[i * 64];
        }
        #pragma unroll
        for (int i = 0; i < CHUNK; ++i) {
            if (i >= cnt) break;
            const float v1 = r1[i & (PF - 1)];
            const float v2 = r2[i & (PF - 1)];
            const float vb = rb[i & (PF - 1)];
            if (i + PF < CHUNK) {
                r1[i & (PF - 1)] = b1[(i + PF) * 64];
                r2[i & (PF - 1)] = b2[(i + PF) * 64];
                rb[i & (PF - 1)] = b3[(i + PF) * 64];
            }
            const float s = wave_sum64(p * vb);
            C2 += __log2f(s);
            p = fmaf(v2 * p, __builtin_amdgcn_rcpf(s), v1);
        }
    };

    if (wave != 0 && nch > 0) p_load(0, 0);

    for (int c = 0; c < nch; ++c) {
        if (wave != 0) {
            if (c + 1 < nch) p_load((c + 1) & 1, c + 1);
            p_write(c & 1, c);
        } else if (c > 0) {
            consume(c - 1);
        }
        __syncthreads();
    }

    if (wave == 0) {
        if (nch > 0) consume(nch - 1);
        const float s = wave_sum64(p * __expf(blv));
        const float total = 0.69314718055994531f * (C2 + __log2f(s));
        if (lane == 0) atomicAdd(out, -total);
    }
}

extern "C" void kernel_launch(void* const* d_in, const int* in_sizes, int n_in,
                              void* d_out, int out_size, void* d_ws, size_t ws_size,
                              hipStream_t stream)
{
    const float* stop    = (const float*)d_in[0];
    const float* start   = (const float*)d_in[1];
    const float* act     = (const float*)d_in[2];
    const int*   actions = (const int*)d_in[3];
    const int*   lengths = (const int*)d_in[4];
    float* out = (float*)d_out;

    const int B   = in_sizes[4];
    const int T   = in_sizes[3] / B;
    const int Tp1 = T + 1;
    const int A   = in_sizes[2] / (B * Tp1 * 64);

    (void)hipMemsetAsync(out, 0, sizeof(float), stream);
    hmm_fwd<<<dim3(B), dim3(256), 0, stream>>>(stop, start, act, actions,
                                               lengths, out, T, A);
}

// Round 5
// 223.624 us; speedup vs baseline: 1.6951x; 1.6951x over previous
//
#include <hip/hip_runtime.h>

// HMM trajectory forward, rank-1+diag rewrite, scaled-probability space.
// R5: time-parallel chunks. Map p -> e1 + e2*(p/S) is scale-invariant and
// mixing; each chunk warms up W steps from uniform, then its partial
// sum of log S stitches exactly (telescoping; entry scale cancels).
// Grid = (B, NC) blocks of one wave; lane = state (b==64).

#define CH   8     // register pipeline depth (double-buffered)
#define WARM 32    // warm-up steps (direction convergence)
#define CLEN 64    // accumulated steps per chunk

template <int CTRL, int RMASK>
__device__ __forceinline__ float dpp_add(float x) {
    int yi = __builtin_amdgcn_update_dpp(
        0, __builtin_bit_cast(int, x), CTRL, RMASK, 0xf, true);
    return x + __builtin_bit_cast(float, yi);
}

// sum over 64 lanes -> wave-uniform scalar
__device__ __forceinline__ float wave_sum64(float x) {
    x = dpp_add<0x111, 0xf>(x);   // row_shr:1
    x = dpp_add<0x112, 0xf>(x);   // row_shr:2
    x = dpp_add<0x114, 0xf>(x);   // row_shr:4
    x = dpp_add<0x118, 0xf>(x);   // row_shr:8
    x = dpp_add<0x142, 0xa>(x);   // row_bcast:15 -> rows 1,3
    x = dpp_add<0x143, 0xc>(x);   // row_bcast:31 -> row 3
    return __builtin_bit_cast(float,
        __builtin_amdgcn_readlane(__builtin_bit_cast(int, x), 63));
}

__global__ __launch_bounds__(64)
void hmm_fwd(const float* __restrict__ stop,     // (B, T+1, 64, 2)
             const float* __restrict__ start,    // (B, T+1, 64)
             const float* __restrict__ act,      // (B, T+1, 64, A)
             const int*   __restrict__ actions,  // (B, T)
             const int*   __restrict__ lengths,  // (B,)
             float* __restrict__ out,            // scalar
             int T, int A)
{
    const int bi   = blockIdx.x;
    const int c    = blockIdx.y;
    const int lane = threadIdx.x;
    const int Tp1  = T + 1;
    const int NB   = 64;
    const int rowA = NB * A;

    const int L = lengths[bi];                     // block-uniform
    const int a = 1 + c * CLEN;                    // first accumulated step
    const int cstar = (L >= 2) ? ((L - 2) / CLEN) : 0;  // terminal chunk
    if (c > cstar) return;

    const int t_end = min(L, a + CLEN);            // exclusive
    const int t0    = (c == 0) ? 1 : (a - WARM);
    const int n     = t_end - t0;                  // 0 possible (L==1, c==0)
    const int nwarm = a - t0;                      // 0 or WARM

    const float* stopB  = stop  + (size_t)bi * Tp1 * NB * 2;
    const float* startB = start + (size_t)bi * Tp1 * NB;
    const float* actB   = act   + (size_t)bi * Tp1 * NB * A;
    const int*   actsB  = actions + (size_t)bi * T;

    // Stage act element-offsets (t*rowA + action[t]) for [t0, t0+n+CH),
    // clamped to t_end-1. Single wave: no barrier needed.
    __shared__ int offL[CLEN + WARM + CH];
    for (int i = lane; i < n + CH; i += 64) {
        const int tt = min(t0 + i, t_end - 1);
        offL[i] = tt * rowA + actsB[tt];
    }

    float p  = (c == 0) ? ((lane == 0) ? 1.0f : 0.0f) : 1.0f;
    float C2 = 0.0f;

    const float* spL = stopB  + (size_t)t0 * (NB * 2) + lane * 2;  // +512B/step
    const float* stL = startB + (size_t)t0 * NB + lane;            // +256B/step
    const int laneA = lane * A;

    float bB[2][CH], bO[2][CH], bS[2][CH], bC[2][CH];

#define LOADF(SL, j) do {                                                    \
    const float* sp  = spL + (size_t)(j) * (CH * NB * 2);                    \
    const float* st2 = stL + (size_t)(j) * (CH * NB);                        \
    _Pragma("unroll")                                                        \
    for (int i = 0; i < CH; ++i) {                                           \
        const float2 so = *(const float2*)(sp + i * (NB * 2));               \
        bB[SL][i] = so.x;                                                    \
        bO[SL][i] = so.y;                                                    \
        bS[SL][i] = st2[i * NB];                                             \
        bC[SL][i] = actB[offL[(j) * CH + i] + laneA];                        \
    } } while (0)

#define LOADC(SL, j) do {                                                    \
    _Pragma("unroll")                                                        \
    for (int i = 0; i < CH; ++i) {                                           \
        const int tt = min(t0 + (j) * CH + i, t_end - 1);                    \
        const float2 so = *(const float2*)(stopB + (size_t)tt * (NB * 2)     \
                                           + lane * 2);                      \
        bB[SL][i] = so.x;                                                    \
        bO[SL][i] = so.y;                                                    \
        bS[SL][i] = startB[(size_t)tt * NB + lane];                          \
        bC[SL][i] = actB[offL[(j) * CH + i] + laneA];                        \
    } } while (0)

#define LOAD(SL, j) do {                                                     \
    if (((j) + 1) * CH <= n) LOADF(SL, j); else LOADC(SL, j); } while (0)

#define COMPUTE(SL, j) do {                                                  \
    _Pragma("unroll")                                                        \
    for (int i = 0; i < CH; ++i) {                                           \
        if ((j) * CH + i < n) {                                              \
            const float e1 = __expf(bC[SL][i] + bS[SL][i]);                  \
            const float e2 = __expf(bC[SL][i] + bO[SL][i]);                  \
            const float eb = __expf(bB[SL][i]);                              \
            const float s  = wave_sum64(p * eb);                             \
            const float l2 = __log2f(s);                                     \
            C2 += ((j) * CH + i >= nwarm) ? l2 : 0.0f;                       \
            p = fmaf(e2 * p, __builtin_amdgcn_rcpf(s), e1);                  \
        }                                                                    \
    } } while (0)

    const int nch = (n + CH - 1) / CH;
    if (n > 0) {
        int j = 0;
        LOAD(0, 0);
        while (true) {
            if (j + 1 < nch) LOAD(1, j + 1);
            COMPUTE(0, j);
            ++j; if (j >= nch) break;
            if (j + 1 < nch) LOAD(0, j + 1);
            COMPUTE(1, j);
            ++j; if (j >= nch) break;
        }
    }

    if (c == cstar) {   // terminal: log(sum_k p[k] * exp(beta_stop[L,k]))
        const float bl = stopB[(size_t)L * (NB * 2) + lane * 2];
        const float s  = wave_sum64(p * __expf(bl));
        C2 += __log2f(s);
    }

    if (lane == 0)
        atomicAdd(out, -0.69314718055994531f * C2);

#undef LOADF
#undef LOADC
#undef LOAD
#undef COMPUTE
}

extern "C" void kernel_launch(void* const* d_in, const int* in_sizes, int n_in,
                              void* d_out, int out_size, void* d_ws, size_t ws_size,
                              hipStream_t stream)
{
    const float* stop    = (const float*)d_in[0];
    const float* start   = (const float*)d_in[1];
    const float* act     = (const float*)d_in[2];
    const int*   actions = (const int*)d_in[3];
    const int*   lengths = (const int*)d_in[4];
    float* out = (float*)d_out;

    const int B   = in_sizes[4];
    const int T   = in_sizes[3] / B;
    const int Tp1 = T + 1;
    const int A   = in_sizes[2] / (B * Tp1 * 64);

    const int NC = (T - 1 + CLEN - 1) / CLEN;   // chunks covering t=1..T-1

    (void)hipMemsetAsync(out, 0, sizeof(float), stream);
    hmm_fwd<<<dim3(B, NC), dim3(64), 0, stream>>>(stop, start, act, actions,
                                                  lengths, out, T, A);
}

// Round 6
// 221.344 us; speedup vs baseline: 1.7126x; 1.0103x over previous
//
#include <hip/hip_runtime.h>

// HMM trajectory forward, rank-1+diag rewrite, scaled-probability space.
// R6: R5 time-parallel chunks +
//  - per-batch ws accumulator slots (64B apart) + trailing reduce kernel
//    (kills ~300-way same-address cross-XCD atomic ping-pong)
//  - CLEN 32 / WARM 16: path 96 -> 48 steps, same total work, 1024 blocks.

#define CH   8     // register pipeline depth (double-buffered)
#define WARM 16    // warm-up steps (direction convergence)
#define CLEN 32    // accumulated steps per chunk
#define SLOT 16    // floats between ws slots (64 B)

template <int CTRL, int RMASK>
__device__ __forceinline__ float dpp_add(float x) {
    int yi = __builtin_amdgcn_update_dpp(
        0, __builtin_bit_cast(int, x), CTRL, RMASK, 0xf, true);
    return x + __builtin_bit_cast(float, yi);
}

// sum over 64 lanes -> wave-uniform scalar
__device__ __forceinline__ float wave_sum64(float x) {
    x = dpp_add<0x111, 0xf>(x);   // row_shr:1
    x = dpp_add<0x112, 0xf>(x);   // row_shr:2
    x = dpp_add<0x114, 0xf>(x);   // row_shr:4
    x = dpp_add<0x118, 0xf>(x);   // row_shr:8
    x = dpp_add<0x142, 0xa>(x);   // row_bcast:15 -> rows 1,3
    x = dpp_add<0x143, 0xc>(x);   // row_bcast:31 -> row 3
    return __builtin_bit_cast(float,
        __builtin_amdgcn_readlane(__builtin_bit_cast(int, x), 63));
}

__global__ __launch_bounds__(64)
void hmm_fwd(const float* __restrict__ stop,     // (B, T+1, 64, 2)
             const float* __restrict__ start,    // (B, T+1, 64)
             const float* __restrict__ act,      // (B, T+1, 64, A)
             const int*   __restrict__ actions,  // (B, T)
             const int*   __restrict__ lengths,  // (B,)
             float* __restrict__ ws,             // (B*SLOT) partial C2 (log2)
             int T, int A)
{
    const int bi   = blockIdx.x;
    const int c    = blockIdx.y;
    const int lane = threadIdx.x;
    const int Tp1  = T + 1;
    const int NB   = 64;
    const int rowA = NB * A;

    const int L = lengths[bi];                     // block-uniform
    const int a = 1 + c * CLEN;                    // first accumulated step
    const int cstar = (L >= 2) ? ((L - 2) / CLEN) : 0;  // terminal chunk
    if (c > cstar) return;

    const int t_end = min(L, a + CLEN);            // exclusive
    const int t0    = (c == 0) ? 1 : (a - WARM);
    const int n     = t_end - t0;                  // 0 possible (L==1, c==0)
    const int nwarm = a - t0;                      // 0 or WARM

    const float* stopB  = stop  + (size_t)bi * Tp1 * NB * 2;
    const float* startB = start + (size_t)bi * Tp1 * NB;
    const float* actB   = act   + (size_t)bi * Tp1 * NB * A;
    const int*   actsB  = actions + (size_t)bi * T;

    // Stage act element-offsets (t*rowA + action[t]) for [t0, t0+n+CH),
    // clamped to t_end-1. Single wave: no barrier needed.
    __shared__ int offL[CLEN + WARM + CH];
    for (int i = lane; i < n + CH; i += 64) {
        const int tt = min(t0 + i, t_end - 1);
        offL[i] = tt * rowA + actsB[tt];
    }

    float p  = (c == 0) ? ((lane == 0) ? 1.0f : 0.0f) : 1.0f;
    float C2 = 0.0f;

    const float* spL = stopB  + (size_t)t0 * (NB * 2) + lane * 2;
    const float* stL = startB + (size_t)t0 * NB + lane;
    const int laneA = lane * A;

    float bB[2][CH], bO[2][CH], bS[2][CH], bC[2][CH];

#define LOADF(SL, j) do {                                                    \
    const float* sp  = spL + (size_t)(j) * (CH * NB * 2);                    \
    const float* st2 = stL + (size_t)(j) * (CH * NB);                        \
    _Pragma("unroll")                                                        \
    for (int i = 0; i < CH; ++i) {                                           \
        const float2 so = *(const float2*)(sp + i * (NB * 2));               \
        bB[SL][i] = so.x;                                                    \
        bO[SL][i] = so.y;                                                    \
        bS[SL][i] = st2[i * NB];                                             \
        bC[SL][i] = actB[offL[(j) * CH + i] + laneA];                        \
    } } while (0)

#define LOADC(SL, j) do {                                                    \
    _Pragma("unroll")                                                        \
    for (int i = 0; i < CH; ++i) {                                           \
        const int tt = min(t0 + (j) * CH + i, t_end - 1);                    \
        const float2 so = *(const float2*)(stopB + (size_t)tt * (NB * 2)     \
                                           + lane * 2);                      \
        bB[SL][i] = so.x;                                                    \
        bO[SL][i] = so.y;                                                    \
        bS[SL][i] = startB[(size_t)tt * NB + lane];                          \
        bC[SL][i] = actB[offL[(j) * CH + i] + laneA];                        \
    } } while (0)

#define LOAD(SL, j) do {                                                     \
    if (((j) + 1) * CH <= n) LOADF(SL, j); else LOADC(SL, j); } while (0)

#define COMPUTE(SL, j) do {                                                  \
    _Pragma("unroll")                                                        \
    for (int i = 0; i < CH; ++i) {                                           \
        if ((j) * CH + i < n) {                                              \
            const float e1 = __expf(bC[SL][i] + bS[SL][i]);                  \
            const float e2 = __expf(bC[SL][i] + bO[SL][i]);                  \
            const float eb = __expf(bB[SL][i]);                              \
            const float s  = wave_sum64(p * eb);                             \
            const float l2 = __log2f(s);                                     \
            C2 += ((j) * CH + i >= nwarm) ? l2 : 0.0f;                       \
            p = fmaf(e2 * p, __builtin_amdgcn_rcpf(s), e1);                  \
        }                                                                    \
    } } while (0)

    const int nch = (n + CH - 1) / CH;
    if (n > 0) {
        int j = 0;
        LOAD(0, 0);
        while (true) {
            if (j + 1 < nch) LOAD(1, j + 1);
            COMPUTE(0, j);
            ++j; if (j >= nch) break;
            if (j + 1 < nch) LOAD(0, j + 1);
            COMPUTE(1, j);
            ++j; if (j >= nch) break;
        }
    }

    if (c == cstar) {   // terminal: log2(sum_k p[k] * exp(beta_stop[L,k]))
        const float bl = stopB[(size_t)L * (NB * 2) + lane * 2];
        const float s  = wave_sum64(p * __expf(bl));
        C2 += __log2f(s);
    }

    if (lane == 0)
        atomicAdd(ws + bi * SLOT, C2);   // per-batch slot, 64B apart

#undef LOADF
#undef LOADC
#undef LOAD
#undef COMPUTE
}

__global__ __launch_bounds__(64)
void hmm_reduce(const float* __restrict__ ws, float* __restrict__ out, int B)
{
    const int lane = threadIdx.x;
    float v = (lane < B) ? ws[lane * SLOT] : 0.0f;
    const float s = wave_sum64(v);
    if (lane == 0)
        out[0] = -0.69314718055994531f * s;
}

extern "C" void kernel_launch(void* const* d_in, const int* in_sizes, int n_in,
                              void* d_out, int out_size, void* d_ws, size_t ws_size,
                              hipStream_t stream)
{
    const float* stop    = (const float*)d_in[0];
    const float* start   = (const float*)d_in[1];
    const float* act     = (const float*)d_in[2];
    const int*   actions = (const int*)d_in[3];
    const int*   lengths = (const int*)d_in[4];
    float* out = (float*)d_out;
    float* ws  = (float*)d_ws;

    const int B   = in_sizes[4];
    const int T   = in_sizes[3] / B;
    const int Tp1 = T + 1;
    const int A   = in_sizes[2] / (B * Tp1 * 64);

    const int NC = (T - 1 + CLEN - 1) / CLEN;   // chunks covering t=1..T-1

    (void)hipMemsetAsync(ws, 0, (size_t)B * SLOT * sizeof(float), stream);
    hmm_fwd<<<dim3(B, NC), dim3(64), 0, stream>>>(stop, start, act, actions,
                                                  lengths, ws, T, A);
    hmm_reduce<<<dim3(1), dim3(64), 0, stream>>>(ws, out, B);
}

// Round 7
// 218.273 us; speedup vs baseline: 1.7367x; 1.0141x over previous
//
#include <hip/hip_runtime.h>

// HMM trajectory forward, rank-1+diag rewrite.
// R7: LINEAR (unnormalized) chunk recurrence: P <- E1*S + E2*P, S = sum(P*EB).
// No per-step rcp/log2 -- power-of-2 renorm every CH steps (exact), chunk
// log-contribution telescopes to two log2's per chunk:
//   nonterminal: log2(S_last) - log2(S_{warm_end})  (+ exponent shifts)
//   terminal:    log2(sum P*EBstop) - log2(S_{warm_end})
// Grid = (B, NC) single-wave blocks; lane = state (b==64).

#define CH   8     // register pipeline depth (double-buffered); renorm cadence
#define WARM 16    // warm-up steps (direction convergence)
#define CLEN 64    // accumulated steps per chunk
#define SLOT 16    // floats between ws slots (64 B)

template <int CTRL, int RMASK>
__device__ __forceinline__ float dpp_add(float x) {
    int yi = __builtin_amdgcn_update_dpp(
        0, __builtin_bit_cast(int, x), CTRL, RMASK, 0xf, true);
    return x + __builtin_bit_cast(float, yi);
}

// sum over 64 lanes -> wave-uniform scalar
__device__ __forceinline__ float wave_sum64(float x) {
    x = dpp_add<0x111, 0xf>(x);   // row_shr:1
    x = dpp_add<0x112, 0xf>(x);   // row_shr:2
    x = dpp_add<0x114, 0xf>(x);   // row_shr:4
    x = dpp_add<0x118, 0xf>(x);   // row_shr:8
    x = dpp_add<0x142, 0xa>(x);   // row_bcast:15 -> rows 1,3
    x = dpp_add<0x143, 0xc>(x);   // row_bcast:31 -> row 3
    return __builtin_bit_cast(float,
        __builtin_amdgcn_readlane(__builtin_bit_cast(int, x), 63));
}

__global__ __launch_bounds__(64)
void hmm_fwd(const float* __restrict__ stop,     // (B, T+1, 64, 2)
             const float* __restrict__ start,    // (B, T+1, 64)
             const float* __restrict__ act,      // (B, T+1, 64, A)
             const int*   __restrict__ actions,  // (B, T)
             const int*   __restrict__ lengths,  // (B,)
             float* __restrict__ ws,             // (B*SLOT) partial C2 (log2)
             int T, int A)
{
    const int bi   = blockIdx.x;
    const int c    = blockIdx.y;
    const int lane = threadIdx.x;
    const int Tp1  = T + 1;
    const int NB   = 64;
    const int rowA = NB * A;

    const int L = lengths[bi];                     // block-uniform
    const int a = 1 + c * CLEN;                    // first accumulated step
    const int cstar = (L >= 2) ? ((L - 2) / CLEN) : 0;  // terminal chunk
    if (c > cstar) return;

    const int t_end = min(L, a + CLEN);            // exclusive
    const int t0    = (c == 0) ? 1 : (a - WARM);
    const int n     = t_end - t0;                  // 0 possible (L==1, c==0)
    const int nwarm = a - t0;                      // 0 or WARM

    const float* stopB  = stop  + (size_t)bi * Tp1 * NB * 2;
    const float* startB = start + (size_t)bi * Tp1 * NB;
    const float* actB   = act   + (size_t)bi * Tp1 * NB * A;
    const int*   actsB  = actions + (size_t)bi * T;

    // Stage act element-offsets (t*rowA + action[t]), clamped to t_end-1.
    __shared__ int offL[CLEN + WARM + CH];
    for (int i = lane; i < n + CH; i += 64) {
        const int tt = min(t0 + i, t_end - 1);
        offL[i] = tt * rowA + actsB[tt];
    }

    float p = (c == 0) ? ((lane == 0) ? 1.0f : 0.0f) : 1.0f;
    float slast   = 1.0f;   // last computed S (kept scale-consistent)
    float warmcap = 0.0f;   // log2 S^u at warm boundary (incl. shifts)
    float Eshift  = 0.0f;   // total pow2 exponent removed so far

    const float* spL = stopB  + (size_t)t0 * (NB * 2) + lane * 2;
    const float* stL = startB + (size_t)t0 * NB + lane;
    const int laneA = lane * A;

    float bB[2][CH], bO[2][CH], bS[2][CH], bC[2][CH];

#define LOADF(SL, j) do {                                                    \
    const float* sp  = spL + (size_t)(j) * (CH * NB * 2);                    \
    const float* st2 = stL + (size_t)(j) * (CH * NB);                        \
    _Pragma("unroll")                                                        \
    for (int i = 0; i < CH; ++i) {                                           \
        bC[SL][i] = actB[offL[(j) * CH + i] + laneA];                        \
        const float2 so = *(const float2*)(sp + i * (NB * 2));               \
        bB[SL][i] = so.x;                                                    \
        bO[SL][i] = so.y;                                                    \
        bS[SL][i] = st2[i * NB];                                             \
    } } while (0)

#define LOADC(SL, j) do {                                                    \
    _Pragma("unroll")                                                        \
    for (int i = 0; i < CH; ++i) {                                           \
        bC[SL][i] = actB[offL[(j) * CH + i] + laneA];                        \
        const int tt = min(t0 + (j) * CH + i, t_end - 1);                    \
        const float2 so = *(const float2*)(stopB + (size_t)tt * (NB * 2)     \
                                           + lane * 2);                      \
        bB[SL][i] = so.x;                                                    \
        bO[SL][i] = so.y;                                                    \
        bS[SL][i] = startB[(size_t)tt * NB + lane];                          \
    } } while (0)

#define LOAD(SL, j) do {                                                     \
    if (((j) + 1) * CH <= n) LOADF(SL, j); else LOADC(SL, j); } while (0)

#define COMPUTE(SL, j) do {                                                  \
    _Pragma("unroll")                                                        \
    for (int i = 0; i < CH; ++i) {                                           \
        if ((j) * CH + i < n) {                                              \
            const float e1 = __expf(bC[SL][i] + bS[SL][i]);                  \
            const float e2 = __expf(bC[SL][i] + bO[SL][i]);                  \
            const float eb = __expf(bB[SL][i]);                              \
            const float q  = e2 * p;             /* overlaps reduction */    \
            const float s  = wave_sum64(p * eb);                             \
            slast = s;                                                       \
            if ((j) * CH + i == nwarm - 1)                                   \
                warmcap = __log2f(s) + Eshift;                               \
            p = fmaf(e1, s, q);                                              \
        }                                                                    \
    }                                                                        \
    /* exact pow2 renorm (once per CH steps) */                              \
    {                                                                        \
        const unsigned sb = __builtin_bit_cast(unsigned, slast);             \
        const int ef = (int)(sb >> 23);          /* biased exponent */       \
        const float sc = __builtin_bit_cast(float,                           \
                             (unsigned)(254 - ef) << 23);   /* 2^-(ef-127) */\
        p *= sc;                                                             \
        slast *= sc;                                                         \
        Eshift += (float)(ef - 127);                                         \
    } } while (0)

    const int nch = (n + CH - 1) / CH;
    if (n > 0) {
        int j = 0;
        LOAD(0, 0);
        while (true) {
            if (j + 1 < nch) LOAD(1, j + 1);
            COMPUTE(0, j);
            ++j; if (j >= nch) break;
            if (j + 1 < nch) LOAD(0, j + 1);
            COMPUTE(1, j);
            ++j; if (j >= nch) break;
        }
    }

    float C2;
    if (c == cstar) {   // terminal: log2(sum_k P[k] * exp(beta_stop[L,k]))
        const float bl = stopB[(size_t)L * (NB * 2) + lane * 2];
        const float s  = wave_sum64(p * __expf(bl));
        C2 = __log2f(s) + Eshift - warmcap;
    } else {
        C2 = __log2f(slast) + Eshift - warmcap;
    }

    if (lane == 0)
        atomicAdd(ws + bi * SLOT, C2);   // per-batch slot, 64B apart

#undef LOADF
#undef LOADC
#undef LOAD
#undef COMPUTE
}

__global__ __launch_bounds__(64)
void hmm_reduce(const float* __restrict__ ws, float* __restrict__ out, int B)
{
    const int lane = threadIdx.x;
    float v = (lane < B) ? ws[lane * SLOT] : 0.0f;
    const float s = wave_sum64(v);
    if (lane == 0)
        out[0] = -0.69314718055994531f * s;
}

extern "C" void kernel_launch(void* const* d_in, const int* in_sizes, int n_in,
                              void* d_out, int out_size, void* d_ws, size_t ws_size,
                              hipStream_t stream)
{
    const float* stop    = (const float*)d_in[0];
    const float* start   = (const float*)d_in[1];
    const float* act     = (const float*)d_in[2];
    const int*   actions = (const int*)d_in[3];
    const int*   lengths = (const int*)d_in[4];
    float* out = (float*)d_out;
    float* ws  = (float*)d_ws;

    const int B   = in_sizes[4];
    const int T   = in_sizes[3] / B;
    const int Tp1 = T + 1;
    const int A   = in_sizes[2] / (B * Tp1 * 64);

    const int NC = (T - 1 + CLEN - 1) / CLEN;   // chunks covering t=1..T-1

    (void)hipMemsetAsync(ws, 0, (size_t)B * SLOT * sizeof(float), stream);
    hmm_fwd<<<dim3(B, NC), dim3(64), 0, stream>>>(stop, start, act, actions,
                                                  lengths, ws, T, A);
    hmm_reduce<<<dim3(1), dim3(64), 0, stream>>>(ws, out, B);
}